// Round 17
// baseline (977.058 us; speedup 1.0000x reference)
//
#include <hip/hip_runtime.h>
#include <hip/hip_bf16.h>

constexpr int TT = 4096;   // tokens
constexpr int HH = 2048;   // hidden
constexpr int II = 2048;   // intermediate
constexpr int EE = 16;     // experts
constexpr int KTOP = 4;    // top-k

typedef __attribute__((ext_vector_type(4))) float f4;
typedef __attribute__((ext_vector_type(8))) short s8;
typedef __attribute__((ext_vector_type(4))) short sh4;

__device__ __forceinline__ short f2bf(float f) {
    union { __hip_bfloat16 b; short s; } u;
    u.b = __float2bfloat16(f);
    return u.s;
}
__device__ __forceinline__ float bf2f(short s) {
    union { unsigned u; float f; } v;
    v.u = ((unsigned)(unsigned short)s) << 16;
    return v.f;
}

// async global->LDS, 16B/lane. LDS dest: wave-uniform base (+lane*16 by HW);
// global source per-lane (gather + swizzle capable).
__device__ __forceinline__ void g2l16(const void* g, void* l) {
    __builtin_amdgcn_global_load_lds(
        (const __attribute__((address_space(1))) void*)g,
        (__attribute__((address_space(3))) void*)l, 16, 0, 0);
}

// ---------------------------------------------------------------------------
// Router + RMSNorm, wave-parallel over experts (round-13-proven).
// ---------------------------------------------------------------------------
__global__ void k_router(const float* __restrict__ x, const float* __restrict__ gamma,
                         const float* __restrict__ wg, const float* __restrict__ bg,
                         short* __restrict__ t16, int* __restrict__ cnt,
                         int* __restrict__ lst, float* __restrict__ lwt) {
    const int tok = blockIdx.x;
    const int lane = threadIdx.x & 63;
    const int w = threadIdx.x >> 6;

    const f4* xr = (const f4*)(x + (size_t)tok * HH);
    const f4* gr = (const f4*)gamma;

    f4 t4[8];
    float ss = 0.f;
#pragma unroll
    for (int j = 0; j < 8; j++) {
        f4 v = xr[lane + 64 * j];
        t4[j] = v;
        ss += v[0] * v[0] + v[1] * v[1] + v[2] * v[2] + v[3] * v[3];
    }
#pragma unroll
    for (int m = 32; m >= 1; m >>= 1) ss += __shfl_xor(ss, m);
    const float rs = rsqrtf(ss * (1.f / HH) + 1e-6f);
#pragma unroll
    for (int j = 0; j < 8; j++) {
        f4 g = gr[lane + 64 * j];
#pragma unroll
        for (int i = 0; i < 4; i++) t4[j][i] *= rs * g[i];
    }

    if (w == 0) {
        short* tr = t16 + (size_t)tok * HH;
#pragma unroll
        for (int j = 0; j < 8; j++) {
            sh4 o;
#pragma unroll
            for (int i = 0; i < 4; i++) o[i] = f2bf(t4[j][i]);
            *(sh4*)(tr + (size_t)(lane + 64 * j) * 4) = o;
        }
    }

    __shared__ float sh_logit[EE];
#pragma unroll
    for (int q = 0; q < 4; q++) {
        const int e = w * 4 + q;
        const f4* wrow = (const f4*)(wg + (size_t)e * HH);
        float a = 0.f;
#pragma unroll
        for (int j = 0; j < 8; j++) {
            f4 wv = wrow[lane + 64 * j];
            a += t4[j][0] * wv[0] + t4[j][1] * wv[1] + t4[j][2] * wv[2] + t4[j][3] * wv[3];
        }
#pragma unroll
        for (int m = 32; m >= 1; m >>= 1) a += __shfl_xor(a, m);
        if (lane == 0) sh_logit[e] = a + bg[e];
    }
    __syncthreads();

    if (threadIdx.x == 0) {
        float logit[EE];
#pragma unroll
        for (int e = 0; e < EE; e++) logit[e] = sh_logit[e];
        unsigned chosen = 0u;
        int sel[KTOP]; float sv[KTOP];
#pragma unroll
        for (int k = 0; k < KTOP; k++) {
            float best = -1e30f; int bi = 0;
#pragma unroll
            for (int e = 0; e < EE; e++) {
                bool take = (!((chosen >> e) & 1u)) && (logit[e] > best);
                if (take) { best = logit[e]; bi = e; }
            }
            chosen |= 1u << bi; sel[k] = bi; sv[k] = best;
        }
        const float lmax = sv[0];
        float s = 0.f;
#pragma unroll
        for (int k = 0; k < KTOP; k++) { sv[k] = expf(sv[k] - lmax); s += sv[k]; }
        const float inv = 1.f / s;
#pragma unroll
        for (int k = 0; k < KTOP; k++) {
            int e = sel[k];
            int p = atomicAdd(&cnt[e], 1);
            lst[e * TT + p] = tok * KTOP + k;
            lwt[e * TT + p] = sv[k] * inv;
        }
    }
}

// ---------------------------------------------------------------------------
// fp32 -> bf16 weight convert (streaming, 8 elems/thread; r2-proven)
// ---------------------------------------------------------------------------
__global__ void k_convert(const float* __restrict__ src, short* __restrict__ dst) {
    size_t i = (size_t)blockIdx.x * 256 + threadIdx.x;
    f4 a = ((const f4*)src)[i * 2];
    f4 b = ((const f4*)src)[i * 2 + 1];
    s8 o;
#pragma unroll
    for (int j = 0; j < 4; j++) { o[j] = f2bf(a[j]); o[4 + j] = f2bf(b[j]); }
    ((s8*)dst)[i] = o;
}

// ---------------------------------------------------------------------------
// FUSED gate+up grouped GEMM: h[pk] = silu(t@w1e^T) * (t@w3e^T).
// 128x128 tile, BK=64, 4 waves, XOR-swizzled LDS. (round-7/9/13/16-proven)
// ---------------------------------------------------------------------------
__global__ __launch_bounds__(256, 2) void k_gemm_ffn_fused(
        const short* __restrict__ t16, const float* __restrict__ w1,
        const float* __restrict__ w3, short* __restrict__ h,
        const int* __restrict__ cnt, const int* __restrict__ lst) {
    const int e = blockIdx.z;
    const int Me = cnt[e];
    const int m0 = blockIdx.y * 128;
    if (m0 >= Me) return;
    const int n0 = blockIdx.x * 128;
    const float* we1 = w1 + (size_t)e * II * HH;   // [N=I][K=H] row-major
    const float* we3 = w3 + (size_t)e * II * HH;

    __shared__ char lA[16384];
    __shared__ char lB1[16384];
    __shared__ char lB2[16384];
    __shared__ int s_tok[128];

    const int tid = threadIdx.x;
    if (tid < 128) s_tok[tid] = (m0 + tid < Me) ? lst[e * TT + m0 + tid] : 0;
    __syncthreads();

    const int lane = tid & 63, wid = tid >> 6;
    const int wr = wid >> 1, wc = wid & 1;

    f4 acc1[4][4], acc2[4][4];
    const f4 zero = {0.f, 0.f, 0.f, 0.f};
#pragma unroll
    for (int i = 0; i < 4; i++)
#pragma unroll
        for (int j = 0; j < 4; j++) { acc1[i][j] = zero; acc2[i][j] = zero; }

    const int rbase = tid >> 3;
    const int kc = (tid & 7) * 8;
    const int lb0 = rbase * 128 + ((kc * 2) ^ ((rbase & 7) << 4));
    int tokrow[4];
#pragma unroll
    for (int j = 0; j < 4; j++) tokrow[j] = s_tok[rbase + 32 * j] >> 2;

    for (int kt = 0; kt < HH / 64; ++kt) {
        __syncthreads();
#pragma unroll
        for (int j = 0; j < 4; j++) {
            s8 av = *(const s8*)(t16 + (size_t)tokrow[j] * HH + kt * 64 + kc);
            *(s8*)(lA + lb0 + 4096 * j) = av;
        }
#pragma unroll
        for (int j = 0; j < 4; j++) {
            size_t roff = (size_t)(n0 + rbase + 32 * j) * HH + kt * 64 + kc;
            {
                f4 b0 = *(const f4*)(we1 + roff);
                f4 b1 = *(const f4*)(we1 + roff + 4);
                s8 bv;
#pragma unroll
                for (int i = 0; i < 4; i++) { bv[i] = f2bf(b0[i]); bv[4 + i] = f2bf(b1[i]); }
                *(s8*)(lB1 + lb0 + 4096 * j) = bv;
            }
            {
                f4 b0 = *(const f4*)(we3 + roff);
                f4 b1 = *(const f4*)(we3 + roff + 4);
                s8 bv;
#pragma unroll
                for (int i = 0; i < 4; i++) { bv[i] = f2bf(b0[i]); bv[4 + i] = f2bf(b1[i]); }
                *(s8*)(lB2 + lb0 + 4096 * j) = bv;
            }
        }
        __syncthreads();
#pragma unroll
        for (int kk = 0; kk < 2; ++kk) {
            s8 af[4], b1v[4], b2v[4];
#pragma unroll
            for (int mf = 0; mf < 4; mf++) {
                int r = wr * 64 + mf * 16 + (lane & 15);
                int byte = r * 128 + (((kk * 64) + ((lane >> 4) << 4)) ^ ((r & 7) << 4));
                af[mf] = *(const s8*)(lA + byte);
            }
#pragma unroll
            for (int nf = 0; nf < 4; nf++) {
                int r = wc * 64 + nf * 16 + (lane & 15);
                int byte = r * 128 + (((kk * 64) + ((lane >> 4) << 4)) ^ ((r & 7) << 4));
                b1v[nf] = *(const s8*)(lB1 + byte);
                b2v[nf] = *(const s8*)(lB2 + byte);
            }
#pragma unroll
            for (int mf = 0; mf < 4; mf++)
#pragma unroll
                for (int nf = 0; nf < 4; nf++) {
                    acc1[mf][nf] = __builtin_amdgcn_mfma_f32_16x16x32_bf16(
                        af[mf], b1v[nf], acc1[mf][nf], 0, 0, 0);
                    acc2[mf][nf] = __builtin_amdgcn_mfma_f32_16x16x32_bf16(
                        af[mf], b2v[nf], acc2[mf][nf], 0, 0, 0);
                }
        }
    }
#pragma unroll
    for (int mf = 0; mf < 4; mf++) {
#pragma unroll
        for (int j = 0; j < 4; j++) {
            int rl = wr * 64 + mf * 16 + ((lane >> 4) << 2) + j;
            if (m0 + rl < Me) {
                size_t orow = (size_t)s_tok[rl] * II;
#pragma unroll
                for (int nf = 0; nf < 4; nf++) {
                    int ncol = n0 + wc * 64 + nf * 16 + (lane & 15);
                    float g = acc1[mf][nf][j];
                    float u = acc2[mf][nf][j];
                    float sg = g / (1.f + expf(-g));
                    h[orow + ncol] = f2bf(sg * u);
                }
            }
        }
    }
}

// ---------------------------------------------------------------------------
// Down GEMM, T3/T4 minimum-2-phase recipe (m248-style): 256x256 tile, BK=64,
// 8 waves (2M x 4N; wave tile 128x64, acc[8][4]=128 AGPR), double-buffered
// LDS (128 KiB), all-DMA staging (bf16 A=h gather, bf16 B=converted w2) with
// pre-swizzled sources (r3-proven 128B-row algebra).
// Loop: STAGE(buf^1, kt+1) -> ds_read/MFMA buf -> vmcnt(0) -> ONE barrier.
// Ledger: STAGE writes the buffer not being read; vmcnt(0)+barrier at step
// end => next step's tile landed block-wide; all ds_reads of buf retired
// before the barrier (compiler data-deps), so next STAGE into it is safe.
// ---------------------------------------------------------------------------
__global__ __launch_bounds__(512, 2) void k_down256(
        const short* __restrict__ h, const short* __restrict__ w2b,
        short* __restrict__ buf2, const int* __restrict__ cnt,
        const int* __restrict__ lst, const float* __restrict__ lwt) {
    const int e = blockIdx.z;
    const int Me = cnt[e];
    const int m0 = blockIdx.y * 256;
    if (m0 >= Me) return;
    const int n0 = blockIdx.x * 256;
    const short* we = w2b + (size_t)e * HH * II;   // bf16 [N=H][K=I]

    __shared__ short lA[2][256 * 64];
    __shared__ short lB[2][256 * 64];
    __shared__ int s_tok[256];
    __shared__ float s_wgt[256];

    const int tid = threadIdx.x;
    if (tid < 256) {
        bool v = (m0 + tid < Me);
        s_tok[tid] = v ? lst[e * TT + m0 + tid] : 0;
        s_wgt[tid] = v ? lwt[e * TT + m0 + tid] : 0.f;
    }
    __syncthreads();

    const int lane = tid & 63, w = tid >> 6;
    const int wr = w >> 2, wcol = w & 3;     // 2M x 4N waves

    // staging sources, pre-swizzled: issue i covers rows i*64+(tid>>3),
    // slot tid&7 holds global chunk (tid&7)^(row&7)  [row&7 == rsub&7].
    const short* ga[4]; const short* gb[4];
    {
        const int rsub = tid >> 3;                       // 0..63
        const int csw = ((tid & 7) ^ (rsub & 7)) * 8;    // chunk in elems
#pragma unroll
        for (int i = 0; i < 4; i++) {
            int row = i * 64 + rsub;
            ga[i] = h + (size_t)s_tok[row] * II + csw;       // pk = h row
            gb[i] = we + (size_t)(n0 + row) * II + csw;
        }
    }

    f4 acc[8][4];
    const f4 zero = {0.f, 0.f, 0.f, 0.f};
#pragma unroll
    for (int i = 0; i < 8; i++)
#pragma unroll
        for (int j = 0; j < 4; j++) acc[i][j] = zero;

#define STG(db, kt)                                                            \
    {                                                                          \
        _Pragma("unroll")                                                      \
        for (int i = 0; i < 4; i++)                                            \
            g2l16(ga[i] + (kt) * 64, (char*)lA[db] + i * 8192 + w * 1024);     \
        _Pragma("unroll")                                                      \
        for (int i = 0; i < 4; i++)                                            \
            g2l16(gb[i] + (kt) * 64, (char*)lB[db] + i * 8192 + w * 1024);     \
    }

    // prologue: stage tile 0, drain, barrier
    STG(0, 0);
    asm volatile("s_waitcnt vmcnt(0)" ::: "memory");
    __builtin_amdgcn_s_barrier();
    asm volatile("" ::: "memory");

    const int nkt = II / 64;   // 32
    int cur = 0;
    for (int kt = 0; kt < nkt; ++kt) {
        // issue next tile's DMA into the buffer NOT being read
        if (kt + 1 < nkt) STG(cur ^ 1, kt + 1);

        // compute tile kt from buf[cur]
#pragma unroll
        for (int kk = 0; kk < 2; ++kk) {
            s8 af[8], bf[4];
#pragma unroll
            for (int mf = 0; mf < 8; mf++) {
                int r = wr * 128 + mf * 16 + (lane & 15);
                int off = (kk * 64 + ((lane >> 4) << 4)) ^ ((r & 7) << 4);
                af[mf] = *(const s8*)((const char*)lA[cur] + r * 128 + off);
            }
#pragma unroll
            for (int nf = 0; nf < 4; nf++) {
                int r = wcol * 64 + nf * 16 + (lane & 15);
                int off = (kk * 64 + ((lane >> 4) << 4)) ^ ((r & 7) << 4);
                bf[nf] = *(const s8*)((const char*)lB[cur] + r * 128 + off);
            }
            __builtin_amdgcn_s_setprio(1);
#pragma unroll
            for (int mf = 0; mf < 8; mf++)
#pragma unroll
                for (int nf = 0; nf < 4; nf++)
                    acc[mf][nf] = __builtin_amdgcn_mfma_f32_16x16x32_bf16(
                        af[mf], bf[nf], acc[mf][nf], 0, 0, 0);
            __builtin_amdgcn_s_setprio(0);
        }

        // end of step: my DMA landed; barrier => everyone's landed
        asm volatile("s_waitcnt vmcnt(0)" ::: "memory");
        asm volatile("" ::: "memory");
        __builtin_amdgcn_s_barrier();
        asm volatile("" ::: "memory");
        cur ^= 1;
    }
#undef STG

    // epilogue: C/D layout col=lane&15, row=(lane>>4)*4+reg
#pragma unroll
    for (int mf = 0; mf < 8; mf++) {
#pragma unroll
        for (int j = 0; j < 4; j++) {
            int rl = wr * 128 + mf * 16 + ((lane >> 4) << 2) + j;
            if (m0 + rl < Me) {
                size_t orow = (size_t)s_tok[rl] * HH;
                float wgt = s_wgt[rl];
#pragma unroll
                for (int nf = 0; nf < 4; nf++) {
                    int ncol = n0 + wcol * 64 + nf * 16 + (lane & 15);
                    buf2[orow + ncol] = f2bf(acc[mf][nf][j] * wgt);
                }
            }
        }
    }
}

// ---------------------------------------------------------------------------
// Final: out = x + sum_k buf2[token*4+k]  (grid-stride, 2048 blocks — G11)
// ---------------------------------------------------------------------------
__global__ void k_final(const float* __restrict__ x, const short* __restrict__ buf2,
                        float* __restrict__ out) {
    const size_t total = (size_t)TT * HH / 8;
    for (size_t i8 = (size_t)blockIdx.x * 256 + threadIdx.x; i8 < total;
         i8 += (size_t)gridDim.x * 256) {
        size_t tok = i8 / (HH / 8);
        size_t c8 = i8 % (HH / 8);
        const f4* xp = (const f4*)x + i8 * 2;
        f4 r0 = xp[0], r1 = xp[1];
#pragma unroll
        for (int k = 0; k < KTOP; k++) {
            s8 b = ((const s8*)buf2)[(tok * KTOP + k) * (HH / 8) + c8];
#pragma unroll
            for (int j = 0; j < 4; j++) { r0[j] += bf2f(b[j]); r1[j] += bf2f(b[4 + j]); }
        }
        ((f4*)out)[i8 * 2] = r0;
        ((f4*)out)[i8 * 2 + 1] = r1;
    }
}

// ---------------------------------------------------------------------------
extern "C" void kernel_launch(void* const* d_in, const int* in_sizes, int n_in,
                              void* d_out, int out_size, void* d_ws, size_t ws_size,
                              hipStream_t stream) {
    const float* x     = (const float*)d_in[0];
    const float* gamma = (const float*)d_in[1];
    const float* wg    = (const float*)d_in[2];
    const float* bg    = (const float*)d_in[3];
    const float* w1    = (const float*)d_in[4];
    const float* w3    = (const float*)d_in[5];
    const float* w2    = (const float*)d_in[6];
    float* out = (float*)d_out;

    char* ws = (char*)d_ws;
    size_t off = 0;
    short* t16  = (short*)(ws + off); off += (size_t)TT * HH * 2;          // 16 MB
    short* h1   = (short*)(ws + off); off += (size_t)TT * KTOP * II * 2;   // 64 MB
    short* buf2 = (short*)(ws + off); off += (size_t)TT * KTOP * HH * 2;   // 64 MB
    short* wbuf = (short*)(ws + off); off += (size_t)EE * HH * II * 2;     // 128 MB
    int* cnt    = (int*)(ws + off); off += 256;
    int* lst    = (int*)(ws + off); off += (size_t)EE * TT * 4;
    float* lwt  = (float*)(ws + off); off += (size_t)EE * TT * 4;

    hipMemsetAsync(cnt, 0, EE * sizeof(int), stream);
    k_router<<<TT, 256, 0, stream>>>(x, gamma, wg, bg, t16, cnt, lst, lwt);

    // convert w2 -> bf16 (independent of ffn; stream-serialized anyway)
    const int convBlocks = (EE * HH * II / 8) / 256;   // 32768
    k_convert<<<convBlocks, 256, 0, stream>>>(w2, wbuf);

    dim3 g1(II / 128, TT / 128, EE);
    k_gemm_ffn_fused<<<g1, 256, 0, stream>>>(t16, w1, w3, h1, cnt, lst);

    dim3 g2(HH / 256, TT / 256, EE);   // 8 x 16 x 16, most m-tiles early-exit
    k_down256<<<g2, 512, 0, stream>>>(h1, wbuf, buf2, cnt, lst, lwt);

    k_final<<<2048, 256, 0, stream>>>(x, buf2, out);
}

// Round 18
// 906.216 us; speedup vs baseline: 1.0782x; 1.0782x over previous
//
#include <hip/hip_runtime.h>
#include <hip/hip_bf16.h>

constexpr int TT = 4096;   // tokens
constexpr int HH = 2048;   // hidden
constexpr int II = 2048;   // intermediate
constexpr int EE = 16;     // experts
constexpr int KTOP = 4;    // top-k

typedef __attribute__((ext_vector_type(4))) float f4;
typedef __attribute__((ext_vector_type(8))) short s8;
typedef __attribute__((ext_vector_type(4))) short sh4;

__device__ __forceinline__ short f2bf(float f) {
    union { __hip_bfloat16 b; short s; } u;
    u.b = __float2bfloat16(f);
    return u.s;
}
__device__ __forceinline__ float bf2f(short s) {
    union { unsigned u; float f; } v;
    v.u = ((unsigned)(unsigned short)s) << 16;
    return v.f;
}

// ---------------------------------------------------------------------------
// Router + RMSNorm, wave-parallel over experts (round-13-proven).
// ---------------------------------------------------------------------------
__global__ void k_router(const float* __restrict__ x, const float* __restrict__ gamma,
                         const float* __restrict__ wg, const float* __restrict__ bg,
                         short* __restrict__ t16, int* __restrict__ cnt,
                         int* __restrict__ lst, float* __restrict__ lwt) {
    const int tok = blockIdx.x;
    const int lane = threadIdx.x & 63;
    const int w = threadIdx.x >> 6;

    const f4* xr = (const f4*)(x + (size_t)tok * HH);
    const f4* gr = (const f4*)gamma;

    f4 t4[8];
    float ss = 0.f;
#pragma unroll
    for (int j = 0; j < 8; j++) {
        f4 v = xr[lane + 64 * j];
        t4[j] = v;
        ss += v[0] * v[0] + v[1] * v[1] + v[2] * v[2] + v[3] * v[3];
    }
#pragma unroll
    for (int m = 32; m >= 1; m >>= 1) ss += __shfl_xor(ss, m);
    const float rs = rsqrtf(ss * (1.f / HH) + 1e-6f);
#pragma unroll
    for (int j = 0; j < 8; j++) {
        f4 g = gr[lane + 64 * j];
#pragma unroll
        for (int i = 0; i < 4; i++) t4[j][i] *= rs * g[i];
    }

    if (w == 0) {
        short* tr = t16 + (size_t)tok * HH;
#pragma unroll
        for (int j = 0; j < 8; j++) {
            sh4 o;
#pragma unroll
            for (int i = 0; i < 4; i++) o[i] = f2bf(t4[j][i]);
            *(sh4*)(tr + (size_t)(lane + 64 * j) * 4) = o;
        }
    }

    __shared__ float sh_logit[EE];
#pragma unroll
    for (int q = 0; q < 4; q++) {
        const int e = w * 4 + q;
        const f4* wrow = (const f4*)(wg + (size_t)e * HH);
        float a = 0.f;
#pragma unroll
        for (int j = 0; j < 8; j++) {
            f4 wv = wrow[lane + 64 * j];
            a += t4[j][0] * wv[0] + t4[j][1] * wv[1] + t4[j][2] * wv[2] + t4[j][3] * wv[3];
        }
#pragma unroll
        for (int m = 32; m >= 1; m >>= 1) a += __shfl_xor(a, m);
        if (lane == 0) sh_logit[e] = a + bg[e];
    }
    __syncthreads();

    if (threadIdx.x == 0) {
        float logit[EE];
#pragma unroll
        for (int e = 0; e < EE; e++) logit[e] = sh_logit[e];
        unsigned chosen = 0u;
        int sel[KTOP]; float sv[KTOP];
#pragma unroll
        for (int k = 0; k < KTOP; k++) {
            float best = -1e30f; int bi = 0;
#pragma unroll
            for (int e = 0; e < EE; e++) {
                bool take = (!((chosen >> e) & 1u)) && (logit[e] > best);
                if (take) { best = logit[e]; bi = e; }
            }
            chosen |= 1u << bi; sel[k] = bi; sv[k] = best;
        }
        const float lmax = sv[0];
        float s = 0.f;
#pragma unroll
        for (int k = 0; k < KTOP; k++) { sv[k] = expf(sv[k] - lmax); s += sv[k]; }
        const float inv = 1.f / s;
#pragma unroll
        for (int k = 0; k < KTOP; k++) {
            int e = sel[k];
            int p = atomicAdd(&cnt[e], 1);
            lst[e * TT + p] = tok * KTOP + k;
            lwt[e * TT + p] = sv[k] * inv;
        }
    }
}

// ---------------------------------------------------------------------------
// FUSED gate+up grouped GEMM: h[pk] = silu(t@w1e^T) * (t@w3e^T).
// 128x128 tile, BK=64, 4 waves, XOR-swizzled LDS. (round-7/9/13/16-proven)
// ---------------------------------------------------------------------------
__global__ __launch_bounds__(256, 2) void k_gemm_ffn_fused(
        const short* __restrict__ t16, const float* __restrict__ w1,
        const float* __restrict__ w3, short* __restrict__ h,
        const int* __restrict__ cnt, const int* __restrict__ lst) {
    const int e = blockIdx.z;
    const int Me = cnt[e];
    const int m0 = blockIdx.y * 128;
    if (m0 >= Me) return;
    const int n0 = blockIdx.x * 128;
    const float* we1 = w1 + (size_t)e * II * HH;   // [N=I][K=H] row-major
    const float* we3 = w3 + (size_t)e * II * HH;

    __shared__ char lA[16384];
    __shared__ char lB1[16384];
    __shared__ char lB2[16384];
    __shared__ int s_tok[128];

    const int tid = threadIdx.x;
    if (tid < 128) s_tok[tid] = (m0 + tid < Me) ? lst[e * TT + m0 + tid] : 0;
    __syncthreads();

    const int lane = tid & 63, wid = tid >> 6;
    const int wr = wid >> 1, wc = wid & 1;

    f4 acc1[4][4], acc2[4][4];
    const f4 zero = {0.f, 0.f, 0.f, 0.f};
#pragma unroll
    for (int i = 0; i < 4; i++)
#pragma unroll
        for (int j = 0; j < 4; j++) { acc1[i][j] = zero; acc2[i][j] = zero; }

    const int rbase = tid >> 3;
    const int kc = (tid & 7) * 8;
    const int lb0 = rbase * 128 + ((kc * 2) ^ ((rbase & 7) << 4));
    int tokrow[4];
#pragma unroll
    for (int j = 0; j < 4; j++) tokrow[j] = s_tok[rbase + 32 * j] >> 2;

    for (int kt = 0; kt < HH / 64; ++kt) {
        __syncthreads();
#pragma unroll
        for (int j = 0; j < 4; j++) {
            s8 av = *(const s8*)(t16 + (size_t)tokrow[j] * HH + kt * 64 + kc);
            *(s8*)(lA + lb0 + 4096 * j) = av;
        }
#pragma unroll
        for (int j = 0; j < 4; j++) {
            size_t roff = (size_t)(n0 + rbase + 32 * j) * HH + kt * 64 + kc;
            {
                f4 b0 = *(const f4*)(we1 + roff);
                f4 b1 = *(const f4*)(we1 + roff + 4);
                s8 bv;
#pragma unroll
                for (int i = 0; i < 4; i++) { bv[i] = f2bf(b0[i]); bv[4 + i] = f2bf(b1[i]); }
                *(s8*)(lB1 + lb0 + 4096 * j) = bv;
            }
            {
                f4 b0 = *(const f4*)(we3 + roff);
                f4 b1 = *(const f4*)(we3 + roff + 4);
                s8 bv;
#pragma unroll
                for (int i = 0; i < 4; i++) { bv[i] = f2bf(b0[i]); bv[4 + i] = f2bf(b1[i]); }
                *(s8*)(lB2 + lb0 + 4096 * j) = bv;
            }
        }
        __syncthreads();
#pragma unroll
        for (int kk = 0; kk < 2; ++kk) {
            s8 af[4], b1v[4], b2v[4];
#pragma unroll
            for (int mf = 0; mf < 4; mf++) {
                int r = wr * 64 + mf * 16 + (lane & 15);
                int byte = r * 128 + (((kk * 64) + ((lane >> 4) << 4)) ^ ((r & 7) << 4));
                af[mf] = *(const s8*)(lA + byte);
            }
#pragma unroll
            for (int nf = 0; nf < 4; nf++) {
                int r = wc * 64 + nf * 16 + (lane & 15);
                int byte = r * 128 + (((kk * 64) + ((lane >> 4) << 4)) ^ ((r & 7) << 4));
                b1v[nf] = *(const s8*)(lB1 + byte);
                b2v[nf] = *(const s8*)(lB2 + byte);
            }
#pragma unroll
            for (int mf = 0; mf < 4; mf++)
#pragma unroll
                for (int nf = 0; nf < 4; nf++) {
                    acc1[mf][nf] = __builtin_amdgcn_mfma_f32_16x16x32_bf16(
                        af[mf], b1v[nf], acc1[mf][nf], 0, 0, 0);
                    acc2[mf][nf] = __builtin_amdgcn_mfma_f32_16x16x32_bf16(
                        af[mf], b2v[nf], acc2[mf][nf], 0, 0, 0);
                }
        }
    }
#pragma unroll
    for (int mf = 0; mf < 4; mf++) {
#pragma unroll
        for (int j = 0; j < 4; j++) {
            int rl = wr * 64 + mf * 16 + ((lane >> 4) << 2) + j;
            if (m0 + rl < Me) {
                size_t orow = (size_t)s_tok[rl] * II;
#pragma unroll
                for (int nf = 0; nf < 4; nf++) {
                    int ncol = n0 + wc * 64 + nf * 16 + (lane & 15);
                    float g = acc1[mf][nf][j];
                    float u = acc2[mf][nf][j];
                    float sg = g / (1.f + expf(-g));
                    h[orow + ncol] = f2bf(sg * u);
                }
            }
        }
    }
}

// ---------------------------------------------------------------------------
// Grouped GEMM (down), round-13-proven: raw barriers (lgkm-only waits) +
// register prefetch of tile kt+1 issued before the compute barrier.
// ---------------------------------------------------------------------------
__global__ __launch_bounds__(256, 2) void k_gemm_down(
        const short* __restrict__ h, const float* __restrict__ w2,
        short* __restrict__ buf2, const int* __restrict__ cnt,
        const int* __restrict__ lst, const float* __restrict__ lwt) {
    const int e = blockIdx.z;
    const int Me = cnt[e];
    const int m0 = blockIdx.y * 128;
    if (m0 >= Me) return;
    const int n0 = blockIdx.x * 128;
    const float* we = w2 + (size_t)e * HH * II;  // [N=H][K=I] row-major

    __shared__ char lA[16384];
    __shared__ char lB[16384];
    __shared__ int s_tok[128];
    __shared__ float s_wgt[128];

    const int tid = threadIdx.x;
    if (tid < 128) {
        bool v = (m0 + tid < Me);
        s_tok[tid] = v ? lst[e * TT + m0 + tid] : 0;
        s_wgt[tid] = v ? lwt[e * TT + m0 + tid] : 0.f;
    }
    __syncthreads();

    const int lane = tid & 63, wid = tid >> 6;
    const int wr = wid >> 1, wc = wid & 1;

    f4 acc[4][4];
    const f4 zero = {0.f, 0.f, 0.f, 0.f};
#pragma unroll
    for (int i = 0; i < 4; i++)
#pragma unroll
        for (int j = 0; j < 4; j++) acc[i][j] = zero;

    const int rbase = tid >> 3;
    const int kc = (tid & 7) * 8;
    const int lb0 = rbase * 128 + ((kc * 2) ^ ((rbase & 7) << 4));
    const short* gA[4]; const float* gB[4];
#pragma unroll
    for (int j = 0; j < 4; j++) {
        gA[j] = h + (size_t)s_tok[rbase + 32 * j] * II + kc;
        gB[j] = we + (size_t)(n0 + rbase + 32 * j) * II + kc;
    }

    s8 ar[4]; f4 br[4][2];
#define PREFETCH(kt)                                                           \
    _Pragma("unroll")                                                          \
    for (int j = 0; j < 4; j++) {                                              \
        ar[j] = *(const s8*)(gA[j] + (kt) * 64);                               \
        br[j][0] = *(const f4*)(gB[j] + (kt) * 64);                            \
        br[j][1] = *(const f4*)(gB[j] + (kt) * 64 + 4);                        \
    }

    PREFETCH(0);
    const int nkt = II / 64;
    for (int kt = 0; kt < nkt; ++kt) {
        asm volatile("" ::: "memory");
        __builtin_amdgcn_s_barrier();
        asm volatile("" ::: "memory");
#pragma unroll
        for (int j = 0; j < 4; j++) {
            *(s8*)(lA + lb0 + 4096 * j) = ar[j];
            s8 bv;
#pragma unroll
            for (int i = 0; i < 4; i++) { bv[i] = f2bf(br[j][0][i]); bv[4 + i] = f2bf(br[j][1][i]); }
            *(s8*)(lB + lb0 + 4096 * j) = bv;
        }
        if (kt + 1 < nkt) PREFETCH(kt + 1);
        asm volatile("s_waitcnt lgkmcnt(0)" ::: "memory");
        __builtin_amdgcn_s_barrier();
        asm volatile("" ::: "memory");
#pragma unroll
        for (int kk = 0; kk < 2; ++kk) {
            s8 af[4], bfr[4];
#pragma unroll
            for (int mf = 0; mf < 4; mf++) {
                int r = wr * 64 + mf * 16 + (lane & 15);
                int byte = r * 128 + (((kk * 64) + ((lane >> 4) << 4)) ^ ((r & 7) << 4));
                af[mf] = *(const s8*)(lA + byte);
            }
#pragma unroll
            for (int nf = 0; nf < 4; nf++) {
                int r = wc * 64 + nf * 16 + (lane & 15);
                int byte = r * 128 + (((kk * 64) + ((lane >> 4) << 4)) ^ ((r & 7) << 4));
                bfr[nf] = *(const s8*)(lB + byte);
            }
#pragma unroll
            for (int mf = 0; mf < 4; mf++)
#pragma unroll
                for (int nf = 0; nf < 4; nf++)
                    acc[mf][nf] = __builtin_amdgcn_mfma_f32_16x16x32_bf16(
                        af[mf], bfr[nf], acc[mf][nf], 0, 0, 0);
        }
    }
#undef PREFETCH
#pragma unroll
    for (int mf = 0; mf < 4; mf++) {
#pragma unroll
        for (int j = 0; j < 4; j++) {
            int rl = wr * 64 + mf * 16 + ((lane >> 4) << 2) + j;
            if (m0 + rl < Me) {
                size_t orow = (size_t)s_tok[rl] * HH;
                float wgt = s_wgt[rl];
#pragma unroll
                for (int nf = 0; nf < 4; nf++) {
                    int ncol = n0 + wc * 64 + nf * 16 + (lane & 15);
                    buf2[orow + ncol] = f2bf(acc[mf][nf][j] * wgt);
                }
            }
        }
    }
}

// ---------------------------------------------------------------------------
// Final: out = x + sum_k buf2[token*4+k]  (grid-stride, 2048 blocks — G11)
// ---------------------------------------------------------------------------
__global__ void k_final(const float* __restrict__ x, const short* __restrict__ buf2,
                        float* __restrict__ out) {
    const size_t total = (size_t)TT * HH / 8;
    for (size_t i8 = (size_t)blockIdx.x * 256 + threadIdx.x; i8 < total;
         i8 += (size_t)gridDim.x * 256) {
        size_t tok = i8 / (HH / 8);
        size_t c8 = i8 % (HH / 8);
        const f4* xp = (const f4*)x + i8 * 2;
        f4 r0 = xp[0], r1 = xp[1];
#pragma unroll
        for (int k = 0; k < KTOP; k++) {
            s8 b = ((const s8*)buf2)[(tok * KTOP + k) * (HH / 8) + c8];
#pragma unroll
            for (int j = 0; j < 4; j++) { r0[j] += bf2f(b[j]); r1[j] += bf2f(b[4 + j]); }
        }
        ((f4*)out)[i8 * 2] = r0;
        ((f4*)out)[i8 * 2 + 1] = r1;
    }
}

// ---------------------------------------------------------------------------
extern "C" void kernel_launch(void* const* d_in, const int* in_sizes, int n_in,
                              void* d_out, int out_size, void* d_ws, size_t ws_size,
                              hipStream_t stream) {
    const float* x     = (const float*)d_in[0];
    const float* gamma = (const float*)d_in[1];
    const float* wg    = (const float*)d_in[2];
    const float* bg    = (const float*)d_in[3];
    const float* w1    = (const float*)d_in[4];
    const float* w3    = (const float*)d_in[5];
    const float* w2    = (const float*)d_in[6];
    float* out = (float*)d_out;

    char* ws = (char*)d_ws;
    size_t off = 0;
    short* t16  = (short*)(ws + off); off += (size_t)TT * HH * 2;          // 16 MB
    short* h1   = (short*)(ws + off); off += (size_t)TT * KTOP * II * 2;   // 64 MB
    short* buf2 = (short*)(ws + off); off += (size_t)TT * KTOP * HH * 2;   // 64 MB
    int* cnt    = (int*)(ws + off); off += 256;
    int* lst    = (int*)(ws + off); off += (size_t)EE * TT * 4;
    float* lwt  = (float*)(ws + off); off += (size_t)EE * TT * 4;

    hipMemsetAsync(cnt, 0, EE * sizeof(int), stream);
    k_router<<<TT, 256, 0, stream>>>(x, gamma, wg, bg, t16, cnt, lst, lwt);

    dim3 g1(II / 128, TT / 128, EE);
    k_gemm_ffn_fused<<<g1, 256, 0, stream>>>(t16, w1, w3, h1, cnt, lst);

    dim3 g2(HH / 128, TT / 128, EE);
    k_gemm_down<<<g2, 256, 0, stream>>>(h1, w2, buf2, cnt, lst, lwt);

    k_final<<<2048, 256, 0, stream>>>(x, buf2, out);
}